// Round 7
// baseline (555.879 us; speedup 1.0000x reference)
//
#include <hip/hip_runtime.h>
#include <hip/hip_bf16.h>

#define NB 64
#define NP 8732
#define NO 32
#define NC 81
#define NROWS (NB * NP)          // 558848 = 2183 * 256 exactly
#define LBLK 2183

// ws layout (16,404 B): [0,16384) u64 bestPrior[NB*NO] packed (iou_bits<<32)|~p
//                       [16384,16400) float accum[4] {cross, l1, iou, npos}
//                       [16400,16404) int flag (1 = f32 inputs, 0 = bf16)
// ROOT CAUSE HISTORY: inputs are FLOAT32 (R2/R6 passed via flag=1 path; every
// hard-coded-bf16 round NaN'd). Keep the runtime flag; dispatch once per kernel.

__device__ __forceinline__ float ldT(const float* p, size_t i) { return p[i]; }
__device__ __forceinline__ float ldT(const unsigned short* p, size_t i) {
    return __uint_as_float((unsigned)p[i] << 16);
}

__global__ void init_kernel(const void* __restrict__ prior,
                            unsigned long long* __restrict__ bestPrior,
                            float* __restrict__ accum, int* __restrict__ flag) {
    int i = threadIdx.x;
    for (int j = i; j < NB * NO; j += blockDim.x) bestPrior[j] = 0ull;
    if (i < 4) accum[i] = 0.0f;
    if (i == 0) {
        const unsigned short* pb = (const unsigned short*)prior;
        int cnt = 0;
        for (int k = 0; k < 128; ++k) {
            float v = __uint_as_float((unsigned)pb[k] << 16);
            if (!(fabsf(v) <= 8.0f)) cnt++;          // catches NaN too
        }
        *flag = (cnt >= 8) ? 1 : 0;                  // f32 read as bf16 -> garbage
    }
}

// Shuffle-free match: thread t = (o = t&31, seg = t>>5) scans 32 consecutive
// priors for object o, strict > keeps first max; packed u64 atomicMax merges
// (larger iou wins; equal iou -> smaller p via ~p, matching jnp.argmax axis=0).
template <typename T>
__device__ __forceinline__ void match_body(
        const T* __restrict__ prior, const T* __restrict__ tb,
        unsigned long long* __restrict__ bestPrior) {
    const int b   = blockIdx.y;
    const int o   = threadIdx.x & 31;
    const int seg = threadIdx.x >> 5;
    const int p0  = blockIdx.x * 256 + seg * 32;

    size_t tbase = ((size_t)(b * NO + o)) * 4;
    float x = ldT(tb, tbase),     y = ldT(tb, tbase + 1);
    float w = ldT(tb, tbase + 2), h = ldT(tb, tbase + 3);
    float tx0 = x, ty0 = y, tx1 = x + w, ty1 = y + h, ta = w * h;

    float bi = -1.0f;
    int bp = 0;
    for (int j = 0; j < 32; ++j) {
        int p = p0 + j;
        if (p >= NP) break;
        size_t pb = (size_t)p * 4;
        float cx = ldT(prior, pb),     cy = ldT(prior, pb + 1);
        float pw = ldT(prior, pb + 2), ph = ldT(prior, pb + 3);
        float px0 = cx - pw * 0.5f, py0 = cy - ph * 0.5f;
        float px1 = cx + pw * 0.5f, py1 = cy + ph * 0.5f;
        float pa = (px1 - px0) * (py1 - py0);
        float lbx = fmaxf(px0, tx0), lby = fmaxf(py0, ty0);
        float ubx = fminf(px1, tx1), uby = fminf(py1, ty1);
        float ww = fmaxf(ubx - lbx, 0.0f), hh = fmaxf(uby - lby, 0.0f);
        float inter = ww * hh;
        float iou = inter / (pa + ta - inter + 1e-6f);
        if (iou > bi) { bi = iou; bp = p; }
    }
    if (bi >= 0.0f) {
        unsigned long long packed =
            (((unsigned long long)__float_as_uint(bi)) << 32) | (~(unsigned)bp);
        atomicMax(&bestPrior[b * NO + o], packed);
    }
}

__global__ __launch_bounds__(256) void match_kernel(
        const void* __restrict__ prior, const void* __restrict__ tb,
        unsigned long long* __restrict__ bestPrior, const int* __restrict__ flag) {
    if (*flag)
        match_body<float>((const float*)prior, (const float*)tb, bestPrior);
    else
        match_body<unsigned short>((const unsigned short*)prior,
                                   (const unsigned short*)tb, bestPrior);
}

// Thread-per-row loss: per-thread 32-object argmax (strict > = first
// occurrence) with force-match fused (ascending o, last wins), per-thread
// log-softmax over 81 classes, box losses for positives.
template <typename T>
__device__ __forceinline__ float4 loss_body(
        const T* __restrict__ plocs, const T* __restrict__ pcls,
        const T* __restrict__ prior, const T* __restrict__ tb,
        const int* __restrict__ tlab,
        const unsigned long long* __restrict__ bestPrior, int row) {
    const int b = row / NP;
    const int p = row - b * NP;

    size_t pb = (size_t)p * 4;
    float cx = ldT(prior, pb),     cy = ldT(prior, pb + 1);
    float pw = ldT(prior, pb + 2), ph = ldT(prior, pb + 3);
    float px0 = cx - pw * 0.5f, py0 = cy - ph * 0.5f;
    float px1 = cx + pw * 0.5f, py1 = cy + ph * 0.5f;
    float pa = (px1 - px0) * (py1 - py0);

    float bi = -1.0f;
    int bo = 0, fo = -1;
    for (int o = 0; o < NO; ++o) {
        size_t tbase = ((size_t)(b * NO + o)) * 4;
        float x = ldT(tb, tbase),     y = ldT(tb, tbase + 1);
        float w = ldT(tb, tbase + 2), h = ldT(tb, tbase + 3);
        float lbx = fmaxf(px0, x),     lby = fmaxf(py0, y);
        float ubx = fminf(px1, x + w), uby = fminf(py1, y + h);
        float ww = fmaxf(ubx - lbx, 0.0f), hh = fmaxf(uby - lby, 0.0f);
        float inter = ww * hh;
        float iou = inter / (pa + w * h - inter + 1e-6f);
        if (iou > bi) { bi = iou; bo = o; }
        if (~(unsigned)(bestPrior[b * NO + o] & 0xffffffffull) == (unsigned)p)
            fo = o;
    }
    if (fo >= 0) { bo = fo; bi = 1.0f; }

    int lab = tlab[b * NO + bo];
    if (bi < 0.5f) lab = 0;

    const T* xr = pcls + (size_t)row * NC;
    float m = -1e30f;
    for (int c = 0; c < NC; ++c) m = fmaxf(m, ldT(xr, c));
    float s = 0.0f;
    for (int c = 0; c < NC; ++c) s += __expf(ldT(xr, c) - m);
    float lse = m + __logf(s);
    float xl = ldT(xr, lab);

    float4 out;
    out.x = lse - xl;          // cross
    out.y = 0.f;               // l1
    out.z = 0.f;               // iou
    out.w = 0.f;               // npos

    if (lab != 0) {
        out.w = 1.0f;
        size_t mb = ((size_t)(b * NO + bo)) * 4;
        float tx = ldT(tb, mb),     ty = ldT(tb, mb + 1);
        float tw = ldT(tb, mb + 2), th = ldT(tb, mb + 3);
        float x0 = tx, y0 = ty, x1 = tx + tw, y1 = ty + th;
        float tcx = (x0 + x1) * 0.5f, tcy = (y0 + y1) * 0.5f;
        size_t lbq = (size_t)row * 4;
        float qcx = ldT(plocs, lbq),     qcy = ldT(plocs, lbq + 1);
        float qw  = ldT(plocs, lbq + 2), qh  = ldT(plocs, lbq + 3);
        out.y = fabsf(qcx - tcx) + fabsf(qcy - tcy)
              + fabsf(qw - tw) + fabsf(qh - th);
        float qX0 = qcx - qw * 0.5f, qY0 = qcy - qh * 0.5f;
        float qX1 = qcx + qw * 0.5f, qY1 = qcy + qh * 0.5f;
        float lbx = fmaxf(x0, qX0), lby = fmaxf(y0, qY0);
        float ubx = fminf(x1, qX1), uby = fminf(y1, qY1);
        float iw = fmaxf(ubx - lbx, 0.f), ih = fmaxf(uby - lby, 0.f);
        float inter = iw * ih;
        float areaq = (qX1 - qX0) * (qY1 - qY0);
        float areat = (x1 - x0) * (y1 - y0);
        out.z = 1.0f - inter / (areat + areaq - inter + 1e-6f);
    }
    return out;
}

__global__ __launch_bounds__(256) void loss_kernel(
        const void* __restrict__ plocs, const void* __restrict__ pcls,
        const void* __restrict__ prior, const void* __restrict__ tb,
        const int* __restrict__ tlab,
        const unsigned long long* __restrict__ bestPrior,
        const int* __restrict__ flag, float* __restrict__ accum) {
    __shared__ float red[4][4];
    const int tid = threadIdx.x;
    const int lane = tid & 63;
    const int wid = tid >> 6;
    const int row = blockIdx.x * 256 + tid;         // exact cover

    float4 s;
    if (*flag)
        s = loss_body<float>((const float*)plocs, (const float*)pcls,
                             (const float*)prior, (const float*)tb,
                             tlab, bestPrior, row);
    else
        s = loss_body<unsigned short>((const unsigned short*)plocs,
                                      (const unsigned short*)pcls,
                                      (const unsigned short*)prior,
                                      (const unsigned short*)tb,
                                      tlab, bestPrior, row);

    for (int d = 1; d < 64; d <<= 1) {
        s.x += __shfl_xor(s.x, d);
        s.y += __shfl_xor(s.y, d);
        s.z += __shfl_xor(s.z, d);
        s.w += __shfl_xor(s.w, d);
    }
    if (lane == 0) { red[wid][0] = s.x; red[wid][1] = s.y;
                     red[wid][2] = s.z; red[wid][3] = s.w; }
    __syncthreads();
    if (tid == 0) {
        float a0 = 0, a1 = 0, a2 = 0, a3 = 0;
        for (int k = 0; k < 4; ++k) { a0 += red[k][0]; a1 += red[k][1];
                                      a2 += red[k][2]; a3 += red[k][3]; }
        atomicAdd(&accum[0], a0);
        atomicAdd(&accum[1], a1);
        atomicAdd(&accum[2], a2);
        atomicAdd(&accum[3], a3);
    }
}

__global__ void finalize_kernel(const float* __restrict__ accum,
                                const int* __restrict__ flag, void* __restrict__ out) {
    if (threadIdx.x == 0) {
        float cross = accum[0] / (float)NROWS;
        float npos = accum[3];
        float loc = accum[1] / (npos * 4.0f);
        float iou = accum[2] / npos;
        if (*flag) {
            float* o = (float*)out;
            o[0] = loc; o[1] = cross; o[2] = iou;
        } else {
            __hip_bfloat16* o = (__hip_bfloat16*)out;
            o[0] = __float2bfloat16(loc);
            o[1] = __float2bfloat16(cross);
            o[2] = __float2bfloat16(iou);
        }
    }
}

extern "C" void kernel_launch(void* const* d_in, const int* in_sizes, int n_in,
                              void* d_out, int out_size, void* d_ws, size_t ws_size,
                              hipStream_t stream) {
    const void* plocs = d_in[0];            // [B,P,4]
    const void* pcls  = d_in[1];            // [B,P,C]
    const void* prior = d_in[2];            // [P,4]
    const void* tb    = d_in[3];            // [B,O,4]
    const int*  tlab  = (const int*)d_in[4];// [B,O]

    char* w = (char*)d_ws;
    unsigned long long* bestPrior = (unsigned long long*)w;      // 16384 B
    float* accum = (float*)(w + 16384);                          // 16 B
    int*   flag  = (int*)(w + 16400);                            // 4 B

    hipLaunchKernelGGL(init_kernel, dim3(1), dim3(256), 0, stream,
                       prior, bestPrior, accum, flag);

    dim3 gA((NP + 255) / 256, NB);
    hipLaunchKernelGGL(match_kernel, gA, dim3(256), 0, stream,
                       prior, tb, bestPrior, flag);

    hipLaunchKernelGGL(loss_kernel, dim3(LBLK), dim3(256), 0, stream,
                       plocs, pcls, prior, tb, tlab, bestPrior, flag, accum);

    hipLaunchKernelGGL(finalize_kernel, dim3(1), dim3(64), 0, stream,
                       accum, flag, d_out);
}

// Round 8
// 397.304 us; speedup vs baseline: 1.3991x; 1.3991x over previous
//
#include <hip/hip_runtime.h>
#include <hip/hip_bf16.h>

#define NB 64
#define NP 8732
#define NO 32
#define NC 81
#define NROWS (NB * NP)          // 558848 = 34928 * 16
#define ITERS (NROWS / 16)       // block-iterations of 16 rows
#define LGRID 2048

// ws layout (16,404 B): [0,16384) u64 bestPrior[NB*NO] packed (iou_bits<<32)|~p
//                       [16384,16400) float accum[4] {cross, l1, iou, npos}
//                       [16400,16404) int flag (1 = f32 inputs, 0 = bf16)
// HISTORY: inputs are FLOAT32 at runtime (flag=1 path is what passes); the
// flag machinery is load-bearing — do not hard-code a dtype.

__device__ __forceinline__ float ldT(const float* p, size_t i) { return p[i]; }
__device__ __forceinline__ float ldT(const unsigned short* p, size_t i) {
    return __uint_as_float((unsigned)p[i] << 16);
}
// 4-elem box load; base element index is a multiple of 4 -> naturally aligned
// (16 B for f32, 8 B for bf16).
__device__ __forceinline__ float4 ld4(const float* p, size_t i) {
    return *(const float4*)(p + i);
}
__device__ __forceinline__ float4 ld4(const unsigned short* p, size_t i) {
    ushort4 u = *(const ushort4*)(p + i);
    return make_float4(__uint_as_float((unsigned)u.x << 16),
                       __uint_as_float((unsigned)u.y << 16),
                       __uint_as_float((unsigned)u.z << 16),
                       __uint_as_float((unsigned)u.w << 16));
}

__global__ void init_kernel(const void* __restrict__ prior,
                            unsigned long long* __restrict__ bestPrior,
                            float* __restrict__ accum, int* __restrict__ flag) {
    int i = threadIdx.x;
    for (int j = i; j < NB * NO; j += blockDim.x) bestPrior[j] = 0ull;
    if (i < 4) accum[i] = 0.0f;
    if (i < 64) {                 // wave 0: parallel dtype sniff on prior
        const unsigned short* pb = (const unsigned short*)prior;
        float v = __uint_as_float((unsigned)pb[i] << 16);
        unsigned long long bad = __ballot(!(fabsf(v) <= 8.0f));
        if (i == 0) *flag = (__popcll(bad) >= 8) ? 1 : 0;
    }
}

// Shuffle-free match (R7-proven): thread t = (o=t&31, seg=t>>5) scans 32
// consecutive priors, strict > keeps first max; packed u64 atomicMax merges
// (larger iou wins; equal iou -> smaller p via ~p).
template <typename T>
__device__ __forceinline__ void match_body(
        const T* __restrict__ prior, const T* __restrict__ tb,
        unsigned long long* __restrict__ bestPrior) {
    const int b   = blockIdx.y;
    const int o   = threadIdx.x & 31;
    const int seg = threadIdx.x >> 5;
    const int p0  = blockIdx.x * 256 + seg * 32;

    float4 t = ld4(tb, ((size_t)(b * NO + o)) * 4);
    float tx0 = t.x, ty0 = t.y, tx1 = t.x + t.z, ty1 = t.y + t.w, ta = t.z * t.w;

    float bi = -1.0f;
    int bp = 0;
    for (int j = 0; j < 32; ++j) {
        int p = p0 + j;
        if (p >= NP) break;
        float4 pr = ld4(prior, (size_t)p * 4);
        float px0 = pr.x - pr.z * 0.5f, py0 = pr.y - pr.w * 0.5f;
        float px1 = pr.x + pr.z * 0.5f, py1 = pr.y + pr.w * 0.5f;
        float pa = (px1 - px0) * (py1 - py0);
        float lbx = fmaxf(px0, tx0), lby = fmaxf(py0, ty0);
        float ubx = fminf(px1, tx1), uby = fminf(py1, ty1);
        float ww = fmaxf(ubx - lbx, 0.0f), hh = fmaxf(uby - lby, 0.0f);
        float inter = ww * hh;
        float iou = inter / (pa + ta - inter + 1e-6f);
        if (iou > bi) { bi = iou; bp = p; }
    }
    if (bi >= 0.0f) {
        unsigned long long packed =
            (((unsigned long long)__float_as_uint(bi)) << 32) | (~(unsigned)bp);
        atomicMax(&bestPrior[b * NO + o], packed);
    }
}

__global__ __launch_bounds__(256) void match_kernel(
        const void* __restrict__ prior, const void* __restrict__ tb,
        unsigned long long* __restrict__ bestPrior, const int* __restrict__ flag) {
    if (*flag)
        match_body<float>((const float*)prior, (const float*)tb, bestPrior);
    else
        match_body<unsigned short>((const unsigned short*)prior,
                                   (const unsigned short*)tb, bestPrior);
}

// 16-lanes-per-row loss: wave = 4 rows (g = lane>>4, q = lane&15).
// CE loads coalesced at c = q+16j; 4-step group reductions; matching via
// 2 objects/lane + tie-aware reduce (first-occurrence argmax preserved).
template <typename T>
__device__ void loss_impl(
        const T* __restrict__ plocs, const T* __restrict__ pcls,
        const T* __restrict__ prior, const T* __restrict__ tb,
        const int* __restrict__ tlab,
        const unsigned long long* __restrict__ bestPrior,
        float* __restrict__ accum) {
    const int tid = threadIdx.x;
    const int lane = tid & 63;
    const int wv = tid >> 6;
    const int q = lane & 15;
    const int g = lane >> 4;

    float c_sum = 0.f, l1_sum = 0.f, iou_sum = 0.f, np_sum = 0.f;

    for (int it = blockIdx.x; it < ITERS; it += gridDim.x) {
        const int row = it * 16 + wv * 4 + g;
        const int b = row / NP;
        const int p = row - b * NP;

        // prior box (broadcast within group)
        float4 pr = ld4(prior, (size_t)p * 4);
        float px0 = pr.x - pr.z * 0.5f, py0 = pr.y - pr.w * 0.5f;
        float px1 = pr.x + pr.z * 0.5f, py1 = pr.y + pr.w * 0.5f;
        float pa = (px1 - px0) * (py1 - py0);

        // objects o=q and o=q+16 (ascending -> strict > keeps smaller o)
        float bi; int bo;
        {
            float4 t = ld4(tb, ((size_t)(b * NO + q)) * 4);
            float lbx = fmaxf(px0, t.x),       lby = fmaxf(py0, t.y);
            float ubx = fminf(px1, t.x + t.z), uby = fminf(py1, t.y + t.w);
            float ww = fmaxf(ubx - lbx, 0.f), hh = fmaxf(uby - lby, 0.f);
            float inter = ww * hh;
            bi = inter / (pa + t.z * t.w - inter + 1e-6f);
            bo = q;
        }
        {
            float4 t = ld4(tb, ((size_t)(b * NO + q + 16)) * 4);
            float lbx = fmaxf(px0, t.x),       lby = fmaxf(py0, t.y);
            float ubx = fminf(px1, t.x + t.z), uby = fminf(py1, t.y + t.w);
            float ww = fmaxf(ubx - lbx, 0.f), hh = fmaxf(uby - lby, 0.f);
            float inter = ww * hh;
            float iou2 = inter / (pa + t.z * t.w - inter + 1e-6f);
            if (iou2 > bi) { bi = iou2; bo = q + 16; }
        }
        // group reduce, tie -> smaller bo (first-occurrence argmax)
        #pragma unroll
        for (int d = 1; d < 16; d <<= 1) {
            float obi = __shfl_xor(bi, d);
            int   obo = __shfl_xor(bo, d);
            if (obi > bi || (obi == bi && obo < bo)) { bi = obi; bo = obo; }
        }
        // force-match: largest matching o wins (proven last-wins semantics)
        int fo = -1;
        if (~(unsigned)(bestPrior[b * NO + q] & 0xffffffffull) == (unsigned)p)
            fo = q;
        if (~(unsigned)(bestPrior[b * NO + q + 16] & 0xffffffffull) == (unsigned)p)
            fo = q + 16;
        #pragma unroll
        for (int d = 1; d < 16; d <<= 1) fo = max(fo, __shfl_xor(fo, d));
        if (fo >= 0) { bo = fo; bi = 1.0f; }

        int lab = tlab[b * NO + bo];
        if (bi < 0.5f) lab = 0;

        // CE: coalesced loads c = q + 16j (j=0..4), + c=80 on q==0
        const T* xr = pcls + (size_t)row * NC;
        float v[5];
        #pragma unroll
        for (int j = 0; j < 5; ++j) v[j] = ldT(xr, q + 16 * j);
        float v80 = (q == 0) ? ldT(xr, 80) : -1e30f;
        float m = fmaxf(fmaxf(fmaxf(v[0], v[1]), fmaxf(v[2], v[3])),
                        fmaxf(v[4], v80));
        #pragma unroll
        for (int d = 1; d < 16; d <<= 1) m = fmaxf(m, __shfl_xor(m, d));
        float s = __expf(v[0] - m) + __expf(v[1] - m) + __expf(v[2] - m)
                + __expf(v[3] - m) + __expf(v[4] - m) + __expf(v80 - m);
        #pragma unroll
        for (int d = 1; d < 16; d <<= 1) s += __shfl_xor(s, d);

        if (q == 0) {
            float lse = m + __logf(s);
            float xl = ldT(xr, lab);
            c_sum += lse - xl;
            if (lab != 0) {                      // R7-verbatim box losses
                np_sum += 1.0f;
                float4 t = ld4(tb, ((size_t)(b * NO + bo)) * 4);
                float x0 = t.x, y0 = t.y, x1 = t.x + t.z, y1 = t.y + t.w;
                float tcx = (x0 + x1) * 0.5f, tcy = (y0 + y1) * 0.5f;
                float4 qv = ld4(plocs, (size_t)row * 4);
                l1_sum += fabsf(qv.x - tcx) + fabsf(qv.y - tcy)
                        + fabsf(qv.z - t.z) + fabsf(qv.w - t.w);
                float qX0 = qv.x - qv.z * 0.5f, qY0 = qv.y - qv.w * 0.5f;
                float qX1 = qv.x + qv.z * 0.5f, qY1 = qv.y + qv.w * 0.5f;
                float lbx = fmaxf(x0, qX0), lby = fmaxf(y0, qY0);
                float ubx = fminf(x1, qX1), uby = fminf(y1, qY1);
                float iw = fmaxf(ubx - lbx, 0.f), ih = fmaxf(uby - lby, 0.f);
                float inter = iw * ih;
                float areaq = (qX1 - qX0) * (qY1 - qY0);
                float areat = (x1 - x0) * (y1 - y0);
                iou_sum += 1.0f - inter / (areat + areaq - inter + 1e-6f);
            }
        }
    }

    // block reduce (once): full-wave butterfly + LDS + 4 atomics
    #pragma unroll
    for (int d = 1; d < 64; d <<= 1) {
        c_sum   += __shfl_xor(c_sum, d);
        l1_sum  += __shfl_xor(l1_sum, d);
        iou_sum += __shfl_xor(iou_sum, d);
        np_sum  += __shfl_xor(np_sum, d);
    }
    __shared__ float red[4][4];
    if (lane == 0) { red[wv][0] = c_sum; red[wv][1] = l1_sum;
                     red[wv][2] = iou_sum; red[wv][3] = np_sum; }
    __syncthreads();
    if (tid == 0) {
        float a0 = 0, a1 = 0, a2 = 0, a3 = 0;
        for (int k = 0; k < 4; ++k) { a0 += red[k][0]; a1 += red[k][1];
                                      a2 += red[k][2]; a3 += red[k][3]; }
        atomicAdd(&accum[0], a0);
        atomicAdd(&accum[1], a1);
        atomicAdd(&accum[2], a2);
        atomicAdd(&accum[3], a3);
    }
}

__global__ __launch_bounds__(256) void loss_kernel(
        const void* __restrict__ plocs, const void* __restrict__ pcls,
        const void* __restrict__ prior, const void* __restrict__ tb,
        const int* __restrict__ tlab,
        const unsigned long long* __restrict__ bestPrior,
        const int* __restrict__ flag, float* __restrict__ accum) {
    if (*flag)
        loss_impl<float>((const float*)plocs, (const float*)pcls,
                         (const float*)prior, (const float*)tb,
                         tlab, bestPrior, accum);
    else
        loss_impl<unsigned short>((const unsigned short*)plocs,
                                  (const unsigned short*)pcls,
                                  (const unsigned short*)prior,
                                  (const unsigned short*)tb,
                                  tlab, bestPrior, accum);
}

__global__ void finalize_kernel(const float* __restrict__ accum,
                                const int* __restrict__ flag, void* __restrict__ out) {
    if (threadIdx.x == 0) {
        float cross = accum[0] / (float)NROWS;
        float npos = accum[3];
        float loc = accum[1] / (npos * 4.0f);
        float iou = accum[2] / npos;
        if (*flag) {
            float* o = (float*)out;
            o[0] = loc; o[1] = cross; o[2] = iou;
        } else {
            __hip_bfloat16* o = (__hip_bfloat16*)out;
            o[0] = __float2bfloat16(loc);
            o[1] = __float2bfloat16(cross);
            o[2] = __float2bfloat16(iou);
        }
    }
}

extern "C" void kernel_launch(void* const* d_in, const int* in_sizes, int n_in,
                              void* d_out, int out_size, void* d_ws, size_t ws_size,
                              hipStream_t stream) {
    const void* plocs = d_in[0];            // [B,P,4]
    const void* pcls  = d_in[1];            // [B,P,C]
    const void* prior = d_in[2];            // [P,4]
    const void* tb    = d_in[3];            // [B,O,4]
    const int*  tlab  = (const int*)d_in[4];// [B,O]

    char* w = (char*)d_ws;
    unsigned long long* bestPrior = (unsigned long long*)w;      // 16384 B
    float* accum = (float*)(w + 16384);                          // 16 B
    int*   flag  = (int*)(w + 16400);                            // 4 B

    hipLaunchKernelGGL(init_kernel, dim3(1), dim3(256), 0, stream,
                       prior, bestPrior, accum, flag);

    dim3 gA((NP + 255) / 256, NB);
    hipLaunchKernelGGL(match_kernel, gA, dim3(256), 0, stream,
                       prior, tb, bestPrior, flag);

    hipLaunchKernelGGL(loss_kernel, dim3(LGRID), dim3(256), 0, stream,
                       plocs, pcls, prior, tb, tlab, bestPrior, flag, accum);

    hipLaunchKernelGGL(finalize_kernel, dim3(1), dim3(64), 0, stream,
                       accum, flag, d_out);
}

// Round 9
// 390.715 us; speedup vs baseline: 1.4227x; 1.0169x over previous
//
#include <hip/hip_runtime.h>
#include <hip/hip_bf16.h>

#define NB 64
#define NP 8732
#define NO 32
#define NC 81
#define NROWS (NB * NP)          // 558848 = 2183*256 = 34928*16
#define PBLK 2183
#define ITERS (NROWS / 16)
#define CGRID 2048

// ws layout: [0,16384)      u64 bestPrior[NB*NO] packed (iou_bits<<32)|~p
//            [16384,16400)  float accum[4] {cross, l1, iou, npos}
//            [16400,16404)  int flag (1 = f32 inputs, 0 = bf16)
//            [16408,575256) u8 lab8[NROWS]
// HISTORY: inputs are FLOAT32 at runtime (flag=1 is the passing path); the
// runtime-dtype flag is load-bearing — do not hard-code a dtype.

__device__ __forceinline__ float ldT(const float* p, size_t i) { return p[i]; }
__device__ __forceinline__ float ldT(const unsigned short* p, size_t i) {
    return __uint_as_float((unsigned)p[i] << 16);
}
__device__ __forceinline__ float4 ld4(const float* p, size_t i) {
    return *(const float4*)(p + i);
}
__device__ __forceinline__ float4 ld4(const unsigned short* p, size_t i) {
    ushort4 u = *(const ushort4*)(p + i);
    return make_float4(__uint_as_float((unsigned)u.x << 16),
                       __uint_as_float((unsigned)u.y << 16),
                       __uint_as_float((unsigned)u.z << 16),
                       __uint_as_float((unsigned)u.w << 16));
}

__global__ void init_kernel(const void* __restrict__ prior,
                            unsigned long long* __restrict__ bestPrior,
                            float* __restrict__ accum, int* __restrict__ flag) {
    int i = threadIdx.x;
    for (int j = i; j < NB * NO; j += blockDim.x) bestPrior[j] = 0ull;
    if (i < 4) accum[i] = 0.0f;
    if (i < 64) {
        const unsigned short* pb = (const unsigned short*)prior;
        float v = __uint_as_float((unsigned)pb[i] << 16);
        unsigned long long bad = __ballot(!(fabsf(v) <= 8.0f));
        if (i == 0) *flag = (__popcll(bad) >= 8) ? 1 : 0;
    }
}

// Per-(b,o) argmax over priors (R7/R8-proven): strict > keeps first max;
// packed u64 atomicMax merges (larger iou wins; ties -> smaller p via ~p).
template <typename T>
__device__ __forceinline__ void match_body(
        const T* __restrict__ prior, const T* __restrict__ tb,
        unsigned long long* __restrict__ bestPrior) {
    const int b   = blockIdx.y;
    const int o   = threadIdx.x & 31;
    const int seg = threadIdx.x >> 5;
    const int p0  = blockIdx.x * 256 + seg * 32;

    float4 t = ld4(tb, ((size_t)(b * NO + o)) * 4);
    float tx0 = t.x, ty0 = t.y, tx1 = t.x + t.z, ty1 = t.y + t.w, ta = t.z * t.w;

    float bi = -1.0f;
    int bp = 0;
    for (int j = 0; j < 32; ++j) {
        int p = p0 + j;
        if (p >= NP) break;
        float4 pr = ld4(prior, (size_t)p * 4);
        float px0 = pr.x - pr.z * 0.5f, py0 = pr.y - pr.w * 0.5f;
        float px1 = pr.x + pr.z * 0.5f, py1 = pr.y + pr.w * 0.5f;
        float pa = (px1 - px0) * (py1 - py0);
        float lbx = fmaxf(px0, tx0), lby = fmaxf(py0, ty0);
        float ubx = fminf(px1, tx1), uby = fminf(py1, ty1);
        float ww = fmaxf(ubx - lbx, 0.0f), hh = fmaxf(uby - lby, 0.0f);
        float inter = ww * hh;
        float iou = inter / (pa + ta - inter + 1e-6f);
        if (iou > bi) { bi = iou; bp = p; }
    }
    if (bi >= 0.0f) {
        unsigned long long packed =
            (((unsigned long long)__float_as_uint(bi)) << 32) | (~(unsigned)bp);
        atomicMax(&bestPrior[b * NO + o], packed);
    }
}

__global__ __launch_bounds__(256) void match_kernel(
        const void* __restrict__ prior, const void* __restrict__ tb,
        unsigned long long* __restrict__ bestPrior, const int* __restrict__ flag) {
    if (*flag)
        match_body<float>((const float*)prior, (const float*)tb, bestPrior);
    else
        match_body<unsigned short>((const unsigned short*)prior,
                                   (const unsigned short*)tb, bestPrior);
}

// Thread-per-row: per-row argmax (strict > = first occurrence) + force-match
// (ascending o, last wins) from LDS-staged per-batch metadata; writes lab8 and
// accumulates l1/iou/npos. Reads no pcls. Box formulas R7-verbatim.
template <typename T>
__device__ void prep_impl(
        const T* __restrict__ plocs, const T* __restrict__ prior,
        const T* __restrict__ tb, const int* __restrict__ tlab,
        const unsigned long long* __restrict__ bestPrior,
        unsigned char* __restrict__ lab8, float* __restrict__ accum) {
    __shared__ float4 s_box[2][NO];          // x0,y0,x1,y1
    __shared__ float  s_area[2][NO];
    __shared__ int    s_lab[2][NO];
    __shared__ unsigned s_forced[2][NO];
    __shared__ float red[4][3];

    const int tid = threadIdx.x;
    const int lane = tid & 63;
    const int wv = tid >> 6;
    const int row = blockIdx.x * 256 + tid;
    const int b = row / NP;
    const int p = row - b * NP;
    const int b0 = (blockIdx.x * 256) / NP;

    if (tid < 64) {
        int bb = tid >> 5, o = tid & 31;
        int bq = b0 + bb;
        if (bq < NB) {
            float4 t = ld4(tb, ((size_t)(bq * NO + o)) * 4);
            s_box[bb][o] = make_float4(t.x, t.y, t.x + t.z, t.y + t.w);
            s_area[bb][o] = t.z * t.w;
            s_lab[bb][o] = tlab[bq * NO + o];
            s_forced[bb][o] = ~(unsigned)(bestPrior[bq * NO + o] & 0xffffffffull);
        }
    }
    __syncthreads();

    const int bb = b - b0;
    float4 pr = ld4(prior, (size_t)p * 4);
    float px0 = pr.x - pr.z * 0.5f, py0 = pr.y - pr.w * 0.5f;
    float px1 = pr.x + pr.z * 0.5f, py1 = pr.y + pr.w * 0.5f;
    float pa = (px1 - px0) * (py1 - py0);

    float bi = -1.0f;
    int bo = 0, fo = -1;
    for (int o = 0; o < NO; ++o) {
        float4 t = s_box[bb][o];
        float lbx = fmaxf(px0, t.x), lby = fmaxf(py0, t.y);
        float ubx = fminf(px1, t.z), uby = fminf(py1, t.w);
        float ww = fmaxf(ubx - lbx, 0.0f), hh = fmaxf(uby - lby, 0.0f);
        float inter = ww * hh;
        float iou = inter / (pa + s_area[bb][o] - inter + 1e-6f);
        if (iou > bi) { bi = iou; bo = o; }
        if (s_forced[bb][o] == (unsigned)p) fo = o;
    }
    if (fo >= 0) { bo = fo; bi = 1.0f; }

    int lab = s_lab[bb][bo];
    if (bi < 0.5f) lab = 0;
    lab8[row] = (unsigned char)lab;

    float l1_sum = 0.f, iou_sum = 0.f, np_sum = 0.f;
    if (lab != 0) {
        np_sum = 1.0f;
        float4 t = s_box[bb][bo];
        float x0 = t.x, y0 = t.y, x1 = t.z, y1 = t.w;
        float tw = x1 - x0, th = y1 - y0;
        // R7 used raw w,h for the l1 terms: reconstruct from staged xyxy is
        // NOT identical; reload raw tb box (L1-hot) to keep bit-proven math.
        float4 traw = ld4(tb, ((size_t)(b * NO + bo)) * 4);
        float tcx = (x0 + x1) * 0.5f, tcy = (y0 + y1) * 0.5f;
        float4 qv = ld4(plocs, (size_t)row * 4);
        l1_sum = fabsf(qv.x - tcx) + fabsf(qv.y - tcy)
               + fabsf(qv.z - traw.z) + fabsf(qv.w - traw.w);
        float qX0 = qv.x - qv.z * 0.5f, qY0 = qv.y - qv.w * 0.5f;
        float qX1 = qv.x + qv.z * 0.5f, qY1 = qv.y + qv.w * 0.5f;
        float lbx = fmaxf(x0, qX0), lby = fmaxf(y0, qY0);
        float ubx = fminf(x1, qX1), uby = fminf(y1, qY1);
        float iw = fmaxf(ubx - lbx, 0.f), ih = fmaxf(uby - lby, 0.f);
        float inter = iw * ih;
        float areaq = (qX1 - qX0) * (qY1 - qY0);
        float areat = (x1 - x0) * (y1 - y0);
        iou_sum = 1.0f - inter / (areat + areaq - inter + 1e-6f);
        (void)tw; (void)th;
    }

    #pragma unroll
    for (int d = 1; d < 64; d <<= 1) {
        l1_sum  += __shfl_xor(l1_sum, d);
        iou_sum += __shfl_xor(iou_sum, d);
        np_sum  += __shfl_xor(np_sum, d);
    }
    if (lane == 0) { red[wv][0] = l1_sum; red[wv][1] = iou_sum; red[wv][2] = np_sum; }
    __syncthreads();
    if (tid == 0) {
        float a1 = 0, a2 = 0, a3 = 0;
        for (int k = 0; k < 4; ++k) { a1 += red[k][0]; a2 += red[k][1]; a3 += red[k][2]; }
        atomicAdd(&accum[1], a1);
        atomicAdd(&accum[2], a2);
        atomicAdd(&accum[3], a3);
    }
}

__global__ __launch_bounds__(256) void prep_kernel(
        const void* __restrict__ plocs, const void* __restrict__ prior,
        const void* __restrict__ tb, const int* __restrict__ tlab,
        const unsigned long long* __restrict__ bestPrior,
        const int* __restrict__ flag,
        unsigned char* __restrict__ lab8, float* __restrict__ accum) {
    if (*flag)
        prep_impl<float>((const float*)plocs, (const float*)prior,
                         (const float*)tb, tlab, bestPrior, lab8, accum);
    else
        prep_impl<unsigned short>((const unsigned short*)plocs,
                                  (const unsigned short*)prior,
                                  (const unsigned short*)tb,
                                  tlab, bestPrior, lab8, accum);
}

// Streaming CE: 16 lanes/row, 4 rows/wave, 2-way unrolled. Chain per row:
// 6 coalesced loads + lab8 gather (L2-hot, independent) -> 8 shuffle steps.
template <typename T>
__device__ void ce_impl(const T* __restrict__ pcls,
                        const unsigned char* __restrict__ lab8,
                        float* __restrict__ accum) {
    const int tid = threadIdx.x;
    const int lane = tid & 63;
    const int wv = tid >> 6;
    const int q = lane & 15;

    float c_sum = 0.f;

    for (int it0 = blockIdx.x; it0 < ITERS; it0 += 2 * CGRID) {
        int it1 = it0 + CGRID;
        bool hasB = (it1 < ITERS);
        int rowA = it0 * 16 + wv * 4 + (lane >> 4);
        int rowB = hasB ? (it1 * 16 + wv * 4 + (lane >> 4)) : rowA;

        int labA = lab8[rowA];
        int labB = lab8[rowB];
        const T* xrA = pcls + (size_t)rowA * NC;
        const T* xrB = pcls + (size_t)rowB * NC;

        float vA[5], vB[5];
        #pragma unroll
        for (int j = 0; j < 5; ++j) { vA[j] = ldT(xrA, q + 16 * j);
                                      vB[j] = ldT(xrB, q + 16 * j); }
        float v80A = (q == 0) ? ldT(xrA, 80) : -1e30f;
        float v80B = (q == 0) ? ldT(xrB, 80) : -1e30f;
        float xlA = (q == 0) ? ldT(xrA, labA) : 0.f;
        float xlB = (q == 0) ? ldT(xrB, labB) : 0.f;

        float mA = fmaxf(fmaxf(fmaxf(vA[0], vA[1]), fmaxf(vA[2], vA[3])),
                         fmaxf(vA[4], v80A));
        float mB = fmaxf(fmaxf(fmaxf(vB[0], vB[1]), fmaxf(vB[2], vB[3])),
                         fmaxf(vB[4], v80B));
        #pragma unroll
        for (int d = 1; d < 16; d <<= 1) {
            mA = fmaxf(mA, __shfl_xor(mA, d));
            mB = fmaxf(mB, __shfl_xor(mB, d));
        }
        float sA = __expf(vA[0] - mA) + __expf(vA[1] - mA) + __expf(vA[2] - mA)
                 + __expf(vA[3] - mA) + __expf(vA[4] - mA) + __expf(v80A - mA);
        float sB = __expf(vB[0] - mB) + __expf(vB[1] - mB) + __expf(vB[2] - mB)
                 + __expf(vB[3] - mB) + __expf(vB[4] - mB) + __expf(v80B - mB);
        #pragma unroll
        for (int d = 1; d < 16; d <<= 1) {
            sA += __shfl_xor(sA, d);
            sB += __shfl_xor(sB, d);
        }
        if (q == 0) {
            c_sum += (mA + __logf(sA)) - xlA;
            if (hasB) c_sum += (mB + __logf(sB)) - xlB;
        }
    }

    #pragma unroll
    for (int d = 1; d < 64; d <<= 1) c_sum += __shfl_xor(c_sum, d);
    __shared__ float red[4];
    if (lane == 0) red[wv] = c_sum;
    __syncthreads();
    if (tid == 0)
        atomicAdd(&accum[0], red[0] + red[1] + red[2] + red[3]);
}

__global__ __launch_bounds__(256) void ce_kernel(
        const void* __restrict__ pcls, const unsigned char* __restrict__ lab8,
        const int* __restrict__ flag, float* __restrict__ accum) {
    if (*flag)
        ce_impl<float>((const float*)pcls, lab8, accum);
    else
        ce_impl<unsigned short>((const unsigned short*)pcls, lab8, accum);
}

__global__ void finalize_kernel(const float* __restrict__ accum,
                                const int* __restrict__ flag, void* __restrict__ out) {
    if (threadIdx.x == 0) {
        float cross = accum[0] / (float)NROWS;
        float npos = accum[3];
        float loc = accum[1] / (npos * 4.0f);
        float iou = accum[2] / npos;
        if (*flag) {
            float* o = (float*)out;
            o[0] = loc; o[1] = cross; o[2] = iou;
        } else {
            __hip_bfloat16* o = (__hip_bfloat16*)out;
            o[0] = __float2bfloat16(loc);
            o[1] = __float2bfloat16(cross);
            o[2] = __float2bfloat16(iou);
        }
    }
}

extern "C" void kernel_launch(void* const* d_in, const int* in_sizes, int n_in,
                              void* d_out, int out_size, void* d_ws, size_t ws_size,
                              hipStream_t stream) {
    const void* plocs = d_in[0];            // [B,P,4]
    const void* pcls  = d_in[1];            // [B,P,C]
    const void* prior = d_in[2];            // [P,4]
    const void* tb    = d_in[3];            // [B,O,4]
    const int*  tlab  = (const int*)d_in[4];// [B,O]

    char* w = (char*)d_ws;
    unsigned long long* bestPrior = (unsigned long long*)w;      // 16384 B
    float* accum = (float*)(w + 16384);                          // 16 B
    int*   flag  = (int*)(w + 16400);                            // 4 B
    unsigned char* lab8 = (unsigned char*)(w + 16408);           // NROWS B

    hipLaunchKernelGGL(init_kernel, dim3(1), dim3(256), 0, stream,
                       prior, bestPrior, accum, flag);

    dim3 gA((NP + 255) / 256, NB);
    hipLaunchKernelGGL(match_kernel, gA, dim3(256), 0, stream,
                       prior, tb, bestPrior, flag);

    hipLaunchKernelGGL(prep_kernel, dim3(PBLK), dim3(256), 0, stream,
                       plocs, prior, tb, tlab, bestPrior, flag, lab8, accum);

    hipLaunchKernelGGL(ce_kernel, dim3(CGRID), dim3(256), 0, stream,
                       pcls, lab8, flag, accum);

    hipLaunchKernelGGL(finalize_kernel, dim3(1), dim3(64), 0, stream,
                       accum, flag, d_out);
}